// Round 3
// baseline (89.238 us; speedup 1.0000x reference)
//
#include <hip/hip_runtime.h>
#include <stdint.h>

// ---------------------------------------------------------------------------
// FastHelgasonLayer, fully fused: weights are IFFTs of 16-sparse spectra
// => exactly rank-32. W_fc = U_fc(2048x32)V_fc(32x8192), W_proj likewise.
// Round 3: barrier-free f-loop (wave-private LDS transpose), 512 blocks x 512
// threads (4 waves/SIMD), exp2-gelu, v_perm bf16 packing, bias via MFMA C-op.
// ---------------------------------------------------------------------------

typedef short bfrag8 __attribute__((ext_vector_type(8)));   // 8 bf16
typedef float f32x4  __attribute__((ext_vector_type(4)));

#define LMASK 8388607u      // 2^23 - 1
#define TWO_PI_OVER_L 7.4901405658478575e-7f

__device__ __forceinline__ unsigned short f2bf(float f) {
    unsigned u = __float_as_uint(f);
    u = (u + 0x7FFFu + ((u >> 16) & 1u)) >> 16;   // RTN-even
    return (unsigned short)u;
}
__device__ __forceinline__ unsigned pk2bf(float a, float b) {
    // two f32 -> packed bf16x2 (round-half-up): 2 adds + 1 v_perm
    unsigned ua = __float_as_uint(a) + 0x8000u;
    unsigned ub = __float_as_uint(b) + 0x8000u;
    return __builtin_amdgcn_perm(ub, ua, 0x07060302u);
}
__device__ __forceinline__ float gelu_fast(float x) {
    // tanh-form gelu via exp2: x * sigmoid(2*0.7978845608*(x+0.044715x^3))
    float xx = x * x;
    float p  = fmaf(xx, 0.044715f, 1.0f);
    float t  = (x * p) * -2.3022083f;             // -2*sqrt(2/pi)*log2(e)
    float e  = __builtin_amdgcn_exp2f(t);
    return x * __builtin_amdgcn_rcpf(1.0f + e);
}

// --------------------------- factor builder (one kernel) -------------------
__device__ __forceinline__ void vt_body(const int* __restrict__ idx,
                                        unsigned short* __restrict__ out, int j) {
    unsigned m = ((unsigned)j) >> 1;
    int p = j & 1;
    #pragma unroll
    for (int k = 0; k < 16; ++k) {
        unsigned s  = ((unsigned)idx[k]) & LMASK;
        unsigned ph = (s * m) & LMASK;
        float sn, cs;
        __sincosf((float)ph * TWO_PI_OVER_L, &sn, &cs);
        float e0 = p ? sn : cs;        // pairs with Re-factor
        float e1 = p ? cs : -sn;       // pairs with Im-factor
        out[(size_t)j * 32 + 2 * k]     = f2bf(e0);
        out[(size_t)j * 32 + 2 * k + 1] = f2bf(e1);
    }
}

__global__ void k_build(const float* __restrict__ fcr, const float* __restrict__ fci,
                        const int* __restrict__ fidx, const float* __restrict__ fcs,
                        const float* __restrict__ prr, const float* __restrict__ pri,
                        const int* __restrict__ pidx, const float* __restrict__ prs,
                        unsigned short* __restrict__ ufct, unsigned short* __restrict__ vtfc,
                        unsigned short* __restrict__ u2t,  unsigned short* __restrict__ vprt) {
    int b = blockIdx.x, t = threadIdx.x;
    if (b < 8) {                       // U_fc^T [32 r][2048 i], carries coeff*scale/L
        int i = b * 256 + t;
        float sc = fcs[0] * (1.0f / 8388608.0f);
        #pragma unroll
        for (int k = 0; k < 16; ++k) {
            int v = fidx[k];
            bool keep = true;          // last-write-wins for duplicate indices
            for (int j = k + 1; j < 16; ++j) keep = keep && (fidx[j] != v);
            unsigned s  = (((unsigned)v) << 12) & LMASK;
            unsigned ph = (s * (unsigned)i) & LMASK;
            float sn, cs;
            __sincosf((float)ph * TWO_PI_OVER_L, &sn, &cs);
            float a = keep ? fcr[k] * sc : 0.0f;
            float bb = keep ? fci[k] * sc : 0.0f;
            ufct[(size_t)(2 * k) * 2048 + i]     = f2bf(a * cs - bb * sn);
            ufct[(size_t)(2 * k + 1) * 2048 + i] = f2bf(a * sn + bb * cs);
        }
    } else if (b < 40) {               // V_fc^T [8192 f][32 r]
        vt_body(fidx, vtfc, (b - 8) * 256 + t);
    } else if (b < 72) {               // U_pr^T [32 r][8192 f], carries coeff*scale/L
        int f = (b - 40) * 256 + t;
        float sc = prs[0] * (1.0f / 8388608.0f);
        #pragma unroll
        for (int k = 0; k < 16; ++k) {
            int v = pidx[k];
            bool keep = true;
            for (int j = k + 1; j < 16; ++j) keep = keep && (pidx[j] != v);
            unsigned s  = (((unsigned)v) << 10) & LMASK;
            unsigned ph = (s * (unsigned)f) & LMASK;
            float sn, cs;
            __sincosf((float)ph * TWO_PI_OVER_L, &sn, &cs);
            float a = keep ? prr[k] * sc : 0.0f;
            float bb = keep ? pri[k] * sc : 0.0f;
            u2t[(size_t)(2 * k) * 8192 + f]     = f2bf(a * cs - bb * sn);
            u2t[(size_t)(2 * k + 1) * 8192 + f] = f2bf(a * sn + bb * cs);
        }
    } else {                           // V_pr^T [2048 d][32 r]
        vt_body(pidx, vprt, (b - 72) * 256 + t);
    }
}

// --------------------------- fused MLP kernel ------------------------------
// 16 tokens/block, 512 blocks, 512 threads (8 waves). f-loop is barrier-free:
// each wave owns f-slices and a private 1KB LDS tile for the h transpose.
__global__ __launch_bounds__(512, 4) void k_fused(
    const float* __restrict__ x,                 // [8192 tok][2048]
    const unsigned short* __restrict__ ufct,     // [32 r][2048 k]
    const unsigned short* __restrict__ vtfc,     // [8192 f][32 r]
    const unsigned short* __restrict__ u2t,      // [32 r][8192 f]
    const unsigned short* __restrict__ vprt,     // [2048 d][32 r]
    const float* __restrict__ fcb,               // [8192]
    const float* __restrict__ prb,               // [2048]
    float* __restrict__ out)                     // [8192 tok][2048]
{
    __shared__ __align__(16) char smem[16384 + 1024 + 8192];
    float*          red = (float*)smem;                    // [8 waves][512]
    unsigned short* lT  = (unsigned short*)(smem + 16384); // [16 tok][32 r]: T1, later T2
    char*           lH  = smem + 16384 + 1024;             // 8 x 1KB wave-private

    const int tid  = threadIdx.x;
    const int w    = tid >> 6;          // wave 0..7
    const int lane = tid & 63;
    const int lr   = lane & 15;
    const int hi   = lane >> 4;         // 0..3
    const size_t tok0 = (size_t)blockIdx.x * 16;

    // ---------------- Phase A: T1 = x_blk @ U_fc (K=2048 split over waves) --
    f32x4 acc[2];
    { f32x4 z = {0.f,0.f,0.f,0.f}; acc[0] = z; acc[1] = z; }
    #pragma unroll 1
    for (int s = 0; s < 8; ++s) {
        int k = w * 256 + s * 32 + hi * 8;
        const float* xp = x + (tok0 + lr) * 2048 + k;
        float4 v0 = *(const float4*)xp;
        float4 v1 = *(const float4*)(xp + 4);
        uint4 aw = make_uint4(pk2bf(v0.x, v0.y), pk2bf(v0.z, v0.w),
                              pk2bf(v1.x, v1.y), pk2bf(v1.z, v1.w));
        bfrag8 af = __builtin_bit_cast(bfrag8, aw);
        bfrag8 b0 = *(const bfrag8*)(ufct + (size_t)lr * 2048 + k);
        bfrag8 b1 = *(const bfrag8*)(ufct + (size_t)(16 + lr) * 2048 + k);
        acc[0] = __builtin_amdgcn_mfma_f32_16x16x32_bf16(af, b0, acc[0], 0, 0, 0);
        acc[1] = __builtin_amdgcn_mfma_f32_16x16x32_bf16(af, b1, acc[1], 0, 0, 0);
    }
    #pragma unroll
    for (int nj = 0; nj < 2; ++nj)
        #pragma unroll
        for (int r = 0; r < 4; ++r)
            red[w * 512 + (hi * 4 + r) * 32 + nj * 16 + lr] = acc[nj][r];
    __syncthreads();
    {
        float s = 0.f;
        #pragma unroll
        for (int w2 = 0; w2 < 8; ++w2) s += red[w2 * 512 + tid];
        lT[tid] = f2bf(s);
    }
    __syncthreads();
    // T1 as B-operand (col=tok, k=r) — loop-invariant
    const bfrag8 t1b = *(const bfrag8*)(lT + lr * 32 + hi * 8);

    // ---------------- Phase B: barrier-free f-loop (32 iters x 32 f/wave) ---
    f32x4 t2acc[2];
    { f32x4 z = {0.f,0.f,0.f,0.f}; t2acc[0] = z; t2acc[1] = z; }
    char* myH = lH + w * 1024;                  // wave-private [16 tok][64 B]
    const int swz = ((lr >> 1) & 3) << 4;       // 16B-granular XOR, <=2-way banks

    auto ldfrag = [&](int it, bfrag8& A0, bfrag8& A1, bfrag8& B0, bfrag8& B1,
                      float4& C0, float4& C1) {
        int fb = it * 256 + w * 32;
        A0 = *(const bfrag8*)(vtfc + (size_t)(fb + lr) * 32 + hi * 8);
        A1 = *(const bfrag8*)(vtfc + (size_t)(fb + 16 + lr) * 32 + hi * 8);
        B0 = *(const bfrag8*)(u2t + (size_t)lr * 8192 + fb + hi * 8);
        B1 = *(const bfrag8*)(u2t + (size_t)(16 + lr) * 8192 + fb + hi * 8);
        C0 = *(const float4*)(fcb + fb + hi * 4);
        C1 = *(const float4*)(fcb + fb + 16 + hi * 4);
    };

    bfrag8 va0, va1, bu0, bu1; float4 cb0, cb1;
    ldfrag(0, va0, va1, bu0, bu1, cb0, cb1);
    #pragma unroll 1
    for (int it = 0; it < 32; ++it) {
        // S = Vfc_chunk(32f x 32r) @ T1^T(32r x 16tok), bias as C-operand
        f32x4 s0 = __builtin_amdgcn_mfma_f32_16x16x32_bf16(va0, t1b, __builtin_bit_cast(f32x4, cb0), 0, 0, 0);
        f32x4 s1 = __builtin_amdgcn_mfma_f32_16x16x32_bf16(va1, t1b, __builtin_bit_cast(f32x4, cb1), 0, 0, 0);
        // prefetch next iter's fragments (L2-resident factors)
        bfrag8 na0, na1, nb0, nb1; float4 nc0, nc1;
        ldfrag((it + 1) & 31, na0, na1, nb0, nb1, nc0, nc1);
        // gelu + pack + wave-private transpose store (no barrier!)
        {
            float g0 = gelu_fast(s0[0]), g1 = gelu_fast(s0[1]);
            float g2 = gelu_fast(s0[2]), g3 = gelu_fast(s0[3]);
            *(uint2*)(myH + lr * 64 + ((hi * 8) ^ swz)) =
                make_uint2(pk2bf(g0, g1), pk2bf(g2, g3));
            float h0 = gelu_fast(s1[0]), h1 = gelu_fast(s1[1]);
            float h2 = gelu_fast(s1[2]), h3 = gelu_fast(s1[3]);
            *(uint2*)(myH + lr * 64 + ((32 + hi * 8) ^ swz)) =
                make_uint2(pk2bf(h0, h1), pk2bf(h2, h3));
        }
        // T2 += h(16tok x 32f) @ U_pr(32f x 32r)  (same-wave LDS readback)
        bfrag8 ha = *(const bfrag8*)(myH + lr * 64 + ((hi * 16) ^ swz));
        t2acc[0] = __builtin_amdgcn_mfma_f32_16x16x32_bf16(ha, bu0, t2acc[0], 0, 0, 0);
        t2acc[1] = __builtin_amdgcn_mfma_f32_16x16x32_bf16(ha, bu1, t2acc[1], 0, 0, 0);
        va0 = na0; va1 = na1; bu0 = nb0; bu1 = nb1; cb0 = nc0; cb1 = nc1;
    }

    // ---------------- T2 cross-wave reduce ----------------------------------
    #pragma unroll
    for (int nj = 0; nj < 2; ++nj)
        #pragma unroll
        for (int r = 0; r < 4; ++r)
            red[w * 512 + (hi * 4 + r) * 32 + nj * 16 + lr] = t2acc[nj][r];
    __syncthreads();
    {
        float s = 0.f;
        #pragma unroll
        for (int w2 = 0; w2 < 8; ++w2) s += red[w2 * 512 + tid];
        lT[tid] = f2bf(s);       // overwrite T1 (t1b already in regs everywhere)
    }
    __syncthreads();

    // ---------------- out = T2 @ V_pr^T + b2 (wave w owns 256 d) ------------
    const bfrag8 t2a = *(const bfrag8*)(lT + lr * 32 + hi * 8);
    #pragma unroll 4
    for (int nj = 0; nj < 16; ++nj) {
        int d = w * 256 + nj * 16 + lr;
        bfrag8 vp = *(const bfrag8*)(vprt + (size_t)d * 32 + hi * 8);
        float bn = prb[d];
        f32x4 c = {bn, bn, bn, bn};
        f32x4 o = __builtin_amdgcn_mfma_f32_16x16x32_bf16(t2a, vp, c, 0, 0, 0);
        #pragma unroll
        for (int r = 0; r < 4; ++r)
            out[(tok0 + hi * 4 + r) * 2048 + d] = o[r];
    }
}

// ---------------------------------------------------------------------------
extern "C" void kernel_launch(void* const* d_in, const int* in_sizes, int n_in,
                              void* d_out, int out_size, void* d_ws, size_t ws_size,
                              hipStream_t stream) {
    (void)in_sizes; (void)n_in; (void)out_size; (void)ws_size;
    const float* x   = (const float*)d_in[0];
    const float* fcr = (const float*)d_in[1];
    const float* fci = (const float*)d_in[2];
    const float* fcs = (const float*)d_in[3];
    const float* prr = (const float*)d_in[4];
    const float* pri = (const float*)d_in[5];
    const float* prs = (const float*)d_in[6];
    const float* fcb = (const float*)d_in[7];
    const float* prb = (const float*)d_in[8];
    const int* fidx  = (const int*)d_in[9];
    const int* pidx  = (const int*)d_in[10];
    float* out = (float*)d_out;
    char* ws = (char*)d_ws;

    size_t off = 0;
    auto take = [&](size_t bytes) { size_t p = off; off = (off + bytes + 255) & ~(size_t)255; return p; };
    unsigned short* ufct = (unsigned short*)(ws + take((size_t)32 * 2048 * 2));   // U_fc^T  [32][2048]
    unsigned short* vtfc = (unsigned short*)(ws + take((size_t)8192 * 32 * 2));   // V_fc^T  [8192][32]
    unsigned short* u2t  = (unsigned short*)(ws + take((size_t)32 * 8192 * 2));   // U_pr^T  [32][8192]
    unsigned short* vprt = (unsigned short*)(ws + take((size_t)2048 * 32 * 2));   // V_pr^T  [2048][32]

    k_build<<<dim3(80), 256, 0, stream>>>(fcr, fci, fidx, fcs, prr, pri, pidx, prs,
                                          ufct, vtfc, u2t, vprt);
    k_fused<<<dim3(512), 512, 0, stream>>>(x, ufct, vtfc, u2t, vprt, fcb, prb, out);
}